// Round 1
// baseline (102.336 us; speedup 1.0000x reference)
//
#include <hip/hip_runtime.h>
#include <math.h>

#define BINSN 50
#define DD 32
#define DD4 (DD / 4)
#define BWF 0.02f            // fp32 of LAST_TIME/BINS, matches jnp weak-typed f32
#define EPSF 1e-6f
#define SQRTPI_HALF 0.88622692545275801f

// ---------------- Kernel A: exclusive cumsum of raw v over bins ----------------
// C[b,n,d] = sum_{k<b} v[k,n,d]   (means cancel in all pairwise differences,
// so no normalization pass is needed anywhere)
__global__ void cumsum_kernel(const float4* __restrict__ v4,
                              float4* __restrict__ C4, int nd4) {
  int idx = blockIdx.x * blockDim.x + threadIdx.x;
  if (idx >= nd4) return;
  float4 run = make_float4(0.f, 0.f, 0.f, 0.f);
  for (int b = 0; b < BINSN; ++b) {
    size_t off = (size_t)b * nd4 + idx;
    C4[off] = run;
    float4 val = v4[off];
    run.x += val.x; run.y += val.y; run.z += val.z; run.w += val.w;
  }
}

// ---------------- Kernel B: -sum(log_intensity) over events ----------------
// 32 lanes per event: lane = dimension d. All row reads are coalesced 128B.
template <bool USE_C>
__global__ void event_kernel(const float* __restrict__ x0,
                             const float* __restrict__ v,
                             const float* __restrict__ C,
                             const float* __restrict__ beta,
                             const float* __restrict__ times,
                             const int* __restrict__ pairs,
                             int N, int E, float* __restrict__ out) {
  const int ND = N * DD;
  const int lane = threadIdx.x & 31;
  int slot = (blockIdx.x * blockDim.x + threadIdx.x) >> 5;
  const int nslots = (gridDim.x * blockDim.x) >> 5;
  float acc = 0.f;
  for (int e = slot; e < E; e += nslots) {
    float t = times[e];
    int p0 = pairs[e];
    int p1 = pairs[E + e];
    int b = (int)floorf(t / BWF);
    b = b < 0 ? 0 : (b > BINSN - 1 ? BINSN - 1 : b);
    float res = fmodf(t, BWF);
    size_t o0 = (size_t)p0 * DD + lane;
    size_t o1 = (size_t)p1 * DD + lane;
    size_t bo = (size_t)b * ND;
    float cum;
    if (USE_C) {
      cum = BWF * (C[bo + o0] - C[bo + o1]);
    } else {
      float c0 = 0.f, c1 = 0.f;
      for (int k = 0; k < b; ++k) {
        size_t ko = (size_t)k * ND;
        c0 += v[ko + o0];
        c1 += v[ko + o1];
      }
      cum = BWF * (c0 - c1);
    }
    float dx = (x0[o0] - x0[o1]) + cum + res * (v[bo + o0] - v[bo + o1]);
    float s = dx * dx;
#pragma unroll
    for (int m = 16; m >= 1; m >>= 1) s += __shfl_xor(s, m, 64);
    if (lane == 0) acc += s - beta[p0] - beta[p1];  // == -log_intensity(e)
  }
  // block reduction -> one atomic per block
#pragma unroll
  for (int m = 32; m >= 1; m >>= 1) acc += __shfl_xor(acc, m, 64);
  __shared__ float smem[16];
  int wid = threadIdx.x >> 6;
  if ((threadIdx.x & 63) == 0) smem[wid] = acc;
  __syncthreads();
  if (threadIdx.x == 0) {
    float tot = 0.f;
    int nw = blockDim.x >> 6;
    for (int w = 0; w < nw; ++w) tot += smem[w];
    atomicAdd(out, tot);
  }
}

// ---------------- Kernel C: survival integral over unique node pairs ----------------
// One thread per pair; sequential over a chunk of bins with running dXt in regs.
template <bool USE_C>
__global__ void integral_kernel(const float4* __restrict__ x04,
                                const float4* __restrict__ v4,
                                const float4* __restrict__ C4,
                                const float* __restrict__ beta,
                                const int* __restrict__ nodes,
                                int N, int S, int npair, int nPairChunks,
                                int bchunk, float* __restrict__ out) {
  const int nd4 = N * DD4;
  int pchunk = blockIdx.x % nPairChunks;
  int binc = blockIdx.x / nPairChunks;
  int p = pchunk * blockDim.x + threadIdx.x;
  float acc = 0.f;
  if (p < npair) {
    const int twoSm1 = 2 * S - 1;
    int i = (int)((twoSm1 - sqrt((double)twoSm1 * twoSm1 - 8.0 * (double)p)) * 0.5);
    if (i < 0) i = 0;
    if (i > S - 2) i = S - 2;
#define BASE(ii) ((ii) * (twoSm1 - (ii)) / 2)
    while (i < S - 2 && BASE(i + 1) <= p) ++i;
    while (i > 0 && BASE(i) > p) --i;
    int j = i + 1 + (p - BASE(i));
#undef BASE
    int u0 = nodes[i], u1 = nodes[j];
    float bij = beta[u0] + beta[u1];
    int b0 = binc * bchunk;
    int b1 = b0 + bchunk; if (b1 > BINSN) b1 = BINSN;
    size_t r0 = (size_t)u0 * DD4;
    size_t r1 = (size_t)u1 * DD4;
    float dxt[DD];
    {
      size_t bo4 = (size_t)b0 * nd4;
#pragma unroll
      for (int q = 0; q < DD4; ++q) {
        float4 a = x04[r0 + q];
        float4 bb = x04[r1 + q];
        float cx = 0.f, cy = 0.f, cz = 0.f, cw = 0.f;
        if (USE_C) {
          float4 ca = C4[bo4 + r0 + q];
          float4 cb = C4[bo4 + r1 + q];
          cx = BWF * (ca.x - cb.x); cy = BWF * (ca.y - cb.y);
          cz = BWF * (ca.z - cb.z); cw = BWF * (ca.w - cb.w);
        }
        dxt[q * 4 + 0] = a.x - bb.x + cx;
        dxt[q * 4 + 1] = a.y - bb.y + cy;
        dxt[q * 4 + 2] = a.z - bb.z + cz;
        dxt[q * 4 + 3] = a.w - bb.w + cw;
      }
    }
    for (int b = b0; b < b1; ++b) {
      size_t bo4 = (size_t)b * nd4;
      float sdd = 0.f, sxd = 0.f, sxx = 0.f;
#pragma unroll
      for (int q = 0; q < DD4; ++q) {
        float4 a = v4[bo4 + r0 + q];
        float4 c = v4[bo4 + r1 + q];
        float dv0 = a.x - c.x, dv1 = a.y - c.y, dv2 = a.z - c.z, dv3 = a.w - c.w;
        float y0 = dxt[q * 4 + 0], y1 = dxt[q * 4 + 1];
        float y2 = dxt[q * 4 + 2], y3 = dxt[q * 4 + 3];
        sdd += dv0 * dv0 + dv1 * dv1 + dv2 * dv2 + dv3 * dv3;
        sxd += y0 * dv0 + y1 * dv1 + y2 * dv2 + y3 * dv3;
        sxx += y0 * y0 + y1 * y1 + y2 * y2 + y3 * y3;
        dxt[q * 4 + 0] = y0 + BWF * dv0;
        dxt[q * 4 + 1] = y1 + BWF * dv1;
        dxt[q * 4 + 2] = y2 + BWF * dv2;
        dxt[q * 4 + 3] = y3 + BWF * dv3;
      }
      float ndv = sqrtf(sdd);
      float inv = 1.0f / (ndv + EPSF);
      float r = sxd * inv;
      float term1 = expf(bij + r * r - sxx);
      float lo = (float)b * BWF * ndv + r;
      float hi = (float)(b + 1) * BWF * ndv + r;
      acc += (SQRTPI_HALF * inv) * term1 * (erff(hi) - erff(lo));
    }
  }
  // block reduction -> one atomic per block
#pragma unroll
  for (int m = 32; m >= 1; m >>= 1) acc += __shfl_xor(acc, m, 64);
  __shared__ float smem[16];
  int wid = threadIdx.x >> 6;
  if ((threadIdx.x & 63) == 0) smem[wid] = acc;
  __syncthreads();
  if (threadIdx.x == 0) {
    float tot = 0.f;
    int nw = blockDim.x >> 6;
    for (int w = 0; w < nw; ++w) tot += smem[w];
    atomicAdd(out, tot);
  }
}

extern "C" void kernel_launch(void* const* d_in, const int* in_sizes, int n_in,
                              void* d_out, int out_size, void* d_ws, size_t ws_size,
                              hipStream_t stream) {
  const float* x0 = (const float*)d_in[0];
  const float* v = (const float*)d_in[1];
  const float* beta = (const float*)d_in[2];
  const float* times = (const float*)d_in[3];
  const int* pairs = (const int*)d_in[4];
  const int* nodes = (const int*)d_in[5];
  int N = in_sizes[2];          // 8192 (beta)
  int E = in_sizes[3];          // 100000
  int S = in_sizes[5];          // 256
  float* out = (float*)d_out;
  float* C = (float*)d_ws;
  size_t needC = (size_t)BINSN * (size_t)N * DD * sizeof(float);
  bool useC = (ws_size >= needC);

  hipMemsetAsync(d_out, 0, (size_t)out_size * sizeof(float), stream);

  if (useC) {
    int nd4 = N * DD4;
    int threads = 256;
    int blocks = (nd4 + threads - 1) / threads;
    cumsum_kernel<<<blocks, threads, 0, stream>>>((const float4*)v, (float4*)C, nd4);
  }

  {
    int threads = 256, blocks = 1024;
    if (useC)
      event_kernel<true><<<blocks, threads, 0, stream>>>(x0, v, C, beta, times, pairs, N, E, out);
    else
      event_kernel<false><<<blocks, threads, 0, stream>>>(x0, v, C, beta, times, pairs, N, E, out);
  }

  {
    int npair = S * (S - 1) / 2;
    int threads = 256;
    int nPairChunks = (npair + threads - 1) / threads;
    int bchunk = useC ? 10 : BINSN;
    int nBinChunks = (BINSN + bchunk - 1) / bchunk;
    int blocks = nPairChunks * nBinChunks;
    if (useC)
      integral_kernel<true><<<blocks, threads, 0, stream>>>(
          (const float4*)x0, (const float4*)v, (const float4*)C, beta, nodes,
          N, S, npair, nPairChunks, bchunk, out);
    else
      integral_kernel<false><<<blocks, threads, 0, stream>>>(
          (const float4*)x0, (const float4*)v, (const float4*)C, beta, nodes,
          N, S, npair, nPairChunks, bchunk, out);
  }
}

// Round 2
// 89.815 us; speedup vs baseline: 1.1394x; 1.1394x over previous
//
#include <hip/hip_runtime.h>
#include <math.h>

#define BINSN 50
#define DD 32
#define DD4 8
#define BWF 0.02f            // fp32 of LAST_TIME/BINS
#define EPSF 1e-6f
#define SQRTPI_HALF 0.8862269254527580f
#define TS 16                // node tile size for integral kernel

// Branch-free erf, Abramowitz-Stegun 7.1.26, |err| <= 1.5e-7 absolute.
__device__ __forceinline__ float fast_erff(float x) {
  float ax = fabsf(x);
  float t = __fdividef(1.0f, fmaf(0.3275911f, ax, 1.0f));
  float p = t * fmaf(t, fmaf(t, fmaf(t, fmaf(t, 1.061405429f, -1.453152027f),
                                     1.421413741f), -0.284496736f), 0.254829592f);
  float y = 1.0f - p * __expf(-ax * ax);
  return copysignf(y, x);
}

// ---------------- Kernel A: positions at bin lower bounds ----------------
// P[b,n,d] = x0[n,d] + BW * sum_{k<b} v[k,n,d]  (normalization means cancel
// in every pairwise difference, so raw x0/v are used)
__global__ void pos_kernel(const float* __restrict__ x0,
                           const float* __restrict__ v,
                           float* __restrict__ P, int ND) {
  int idx = blockIdx.x * blockDim.x + threadIdx.x;
  if (idx >= ND) return;
  float run = x0[idx];
#pragma unroll 10
  for (int b = 0; b < BINSN; ++b) {
    size_t off = (size_t)b * ND + idx;
    P[off] = run;
    run = fmaf(BWF, v[off], run);
  }
}

// ---------------- Kernel B: -sum(log_intensity) over events ----------------
// 32 lanes per event (lane = dimension). 4 coalesced 128B row gathers/event.
__global__ void event_kernel_p(const float* __restrict__ P,
                               const float* __restrict__ v,
                               const float* __restrict__ beta,
                               const float* __restrict__ times,
                               const int* __restrict__ pairs,
                               int N, int E, float* __restrict__ out) {
  const int ND = N * DD;
  const int lane = threadIdx.x & 31;
  int slot = (blockIdx.x * blockDim.x + threadIdx.x) >> 5;
  const int nslots = (gridDim.x * blockDim.x) >> 5;
  float acc = 0.f;
  for (int e = slot; e < E; e += nslots) {
    float t = times[e];
    int p0 = pairs[e];
    int p1 = pairs[E + e];
    int b = (int)floorf(t / BWF);
    b = b < 0 ? 0 : (b > BINSN - 1 ? BINSN - 1 : b);
    float res = fmodf(t, BWF);
    size_t o0 = (size_t)p0 * DD + lane;
    size_t o1 = (size_t)p1 * DD + lane;
    size_t bo = (size_t)b * ND;
    float dx = (P[bo + o0] - P[bo + o1]) + res * (v[bo + o0] - v[bo + o1]);
    float s = dx * dx;
#pragma unroll
    for (int m = 16; m >= 1; m >>= 1) s += __shfl_xor(s, m, 64);
    if (lane == 0) acc += s - beta[p0] - beta[p1];
  }
#pragma unroll
  for (int m = 32; m >= 1; m >>= 1) acc += __shfl_xor(acc, m, 64);
  __shared__ float smem[16];
  int wid = threadIdx.x >> 6;
  if ((threadIdx.x & 63) == 0) smem[wid] = acc;
  __syncthreads();
  if (threadIdx.x == 0) {
    float tot = 0.f;
    int nw = blockDim.x >> 6;
    for (int w = 0; w < nw; ++w) tot += smem[w];
    atomicAdd(out, tot);
  }
}

// ---------------- Kernel C: survival integral, tiled 16x16 node pairs ----------------
// Block = (triangular tile ti<=tj) x (bin chunk). 256 threads = 16x16 pairs.
// Per bin: stage 32 v-rows (4KB) into double-buffered padded LDS; each thread
// keeps its running dXt[32] in registers.
__global__ void integral_tiled(const float4* __restrict__ P4,
                               const float4* __restrict__ v4,
                               const float* __restrict__ beta,
                               const int* __restrict__ nodes,
                               int N, int S, int nTileRows, int nTiles,
                               int bchunk, float* __restrict__ out) {
  const int nd4 = N * DD4;
  int tile = blockIdx.x % nTiles;
  int binc = blockIdx.x / nTiles;
  int ti = 0;
  {
    int rem = tile;
    while (rem >= nTileRows - ti) { rem -= (nTileRows - ti); ++ti; }
    tile = rem;
  }
  int tj = ti + tile;

  int tx = threadIdx.x;
  int il = tx >> 4, jl = tx & 15;
  int gi = ti * TS + il, gj = tj * TS + jl;
  bool valid = (gi < gj) && (gj < S);
  int u0 = valid ? nodes[gi] : 0;
  int u1 = valid ? nodes[gj] : 0;
  float bij = valid ? (beta[u0] + beta[u1]) : 0.f;

  int b0 = binc * bchunk;
  int b1 = b0 + bchunk; if (b1 > BINSN) b1 = BINSN;

  __shared__ float bufA[32][36];   // pad 32 -> 36 floats: ds_read_b128 is 2-way (free)
  __shared__ float bufB[32][36];

  // staging role: 32 rows x 8 float4, one float4 per thread
  int srow = tx >> 3;
  int sq = tx & 7;
  int grow = (srow < TS) ? (ti * TS + srow) : (tj * TS + (srow - TS));
  if (grow >= S) grow = S - 1;
  int snode = nodes[grow];
  size_t sgbase = (size_t)snode * DD4 + sq;

  // ---- seed dXt from P[b0] ----
  *(float4*)&bufA[srow][sq * 4] = P4[(size_t)b0 * nd4 + sgbase];
  __syncthreads();
  float dxt[DD];
  if (valid) {
#pragma unroll
    for (int q = 0; q < DD4; ++q) {
      float4 a = *(const float4*)&bufA[il][q * 4];
      float4 b = *(const float4*)&bufA[TS + jl][q * 4];
      dxt[q * 4 + 0] = a.x - b.x;
      dxt[q * 4 + 1] = a.y - b.y;
      dxt[q * 4 + 2] = a.z - b.z;
      dxt[q * 4 + 3] = a.w - b.w;
    }
  }
  __syncthreads();
  // stage v[b0] into bufA
  *(float4*)&bufA[srow][sq * 4] = v4[(size_t)b0 * nd4 + sgbase];
  __syncthreads();

  float acc = 0.f;
  for (int b = b0; b < b1; ++b) {
    float* cur = ((b - b0) & 1) ? &bufB[0][0] : &bufA[0][0];
    float* nxt = ((b - b0) & 1) ? &bufA[0][0] : &bufB[0][0];
    if (b + 1 < b1)   // prefetch next bin's rows into the other buffer
      *(float4*)&nxt[srow * 36 + sq * 4] = v4[(size_t)(b + 1) * nd4 + sgbase];
    if (valid) {
      float sdd = 0.f, sxd = 0.f, sxx = 0.f;
#pragma unroll
      for (int q = 0; q < DD4; ++q) {
        float4 a = *(const float4*)&cur[il * 36 + q * 4];
        float4 c = *(const float4*)&cur[(TS + jl) * 36 + q * 4];
        float d0 = a.x - c.x, d1 = a.y - c.y, d2 = a.z - c.z, d3 = a.w - c.w;
        float y0 = dxt[q * 4 + 0], y1 = dxt[q * 4 + 1];
        float y2 = dxt[q * 4 + 2], y3 = dxt[q * 4 + 3];
        sdd += d0 * d0 + d1 * d1 + d2 * d2 + d3 * d3;
        sxd += y0 * d0 + y1 * d1 + y2 * d2 + y3 * d3;
        sxx += y0 * y0 + y1 * y1 + y2 * y2 + y3 * y3;
        dxt[q * 4 + 0] = fmaf(BWF, d0, y0);
        dxt[q * 4 + 1] = fmaf(BWF, d1, y1);
        dxt[q * 4 + 2] = fmaf(BWF, d2, y2);
        dxt[q * 4 + 3] = fmaf(BWF, d3, y3);
      }
      float ndv = sqrtf(sdd);
      float inv = __fdividef(1.0f, ndv + EPSF);
      float r = sxd * inv;
      float t1 = __expf(bij + r * r - sxx);   // r^2 <= sxx (Cauchy-Schwarz): bounded
      float lo = fmaf((float)b * BWF, ndv, r);
      float hi = fmaf((float)(b + 1) * BWF, ndv, r);
      acc += SQRTPI_HALF * inv * t1 * (fast_erff(hi) - fast_erff(lo));
    }
    __syncthreads();
  }

#pragma unroll
  for (int m = 32; m >= 1; m >>= 1) acc += __shfl_xor(acc, m, 64);
  __shared__ float smem[16];
  int wid = threadIdx.x >> 6;
  if ((threadIdx.x & 63) == 0) smem[wid] = acc;
  __syncthreads();
  if (threadIdx.x == 0) {
    float tot = 0.f;
    int nw = blockDim.x >> 6;
    for (int w = 0; w < nw; ++w) tot += smem[w];
    atomicAdd(out, tot);
  }
}

// ---------------- Fallback kernels (workspace too small): recompute cumsum ----------------
__global__ void event_kernel_fb(const float* __restrict__ x0,
                                const float* __restrict__ v,
                                const float* __restrict__ beta,
                                const float* __restrict__ times,
                                const int* __restrict__ pairs,
                                int N, int E, float* __restrict__ out) {
  const int ND = N * DD;
  const int lane = threadIdx.x & 31;
  int slot = (blockIdx.x * blockDim.x + threadIdx.x) >> 5;
  const int nslots = (gridDim.x * blockDim.x) >> 5;
  float acc = 0.f;
  for (int e = slot; e < E; e += nslots) {
    float t = times[e];
    int p0 = pairs[e];
    int p1 = pairs[E + e];
    int b = (int)floorf(t / BWF);
    b = b < 0 ? 0 : (b > BINSN - 1 ? BINSN - 1 : b);
    float res = fmodf(t, BWF);
    size_t o0 = (size_t)p0 * DD + lane;
    size_t o1 = (size_t)p1 * DD + lane;
    size_t bo = (size_t)b * ND;
    float c0 = 0.f, c1 = 0.f;
    for (int k = 0; k < b; ++k) {
      size_t ko = (size_t)k * ND;
      c0 += v[ko + o0];
      c1 += v[ko + o1];
    }
    float dx = (x0[o0] - x0[o1]) + BWF * (c0 - c1) + res * (v[bo + o0] - v[bo + o1]);
    float s = dx * dx;
#pragma unroll
    for (int m = 16; m >= 1; m >>= 1) s += __shfl_xor(s, m, 64);
    if (lane == 0) acc += s - beta[p0] - beta[p1];
  }
#pragma unroll
  for (int m = 32; m >= 1; m >>= 1) acc += __shfl_xor(acc, m, 64);
  __shared__ float smem[16];
  int wid = threadIdx.x >> 6;
  if ((threadIdx.x & 63) == 0) smem[wid] = acc;
  __syncthreads();
  if (threadIdx.x == 0) {
    float tot = 0.f;
    int nw = blockDim.x >> 6;
    for (int w = 0; w < nw; ++w) tot += smem[w];
    atomicAdd(out, tot);
  }
}

__global__ void integral_fb(const float4* __restrict__ x04,
                            const float4* __restrict__ v4,
                            const float* __restrict__ beta,
                            const int* __restrict__ nodes,
                            int N, int S, int npair, int nPairChunks,
                            float* __restrict__ out) {
  const int nd4 = N * DD4;
  int p = (blockIdx.x % nPairChunks) * blockDim.x + threadIdx.x;
  float acc = 0.f;
  if (p < npair) {
    const int twoSm1 = 2 * S - 1;
    int i = (int)((twoSm1 - sqrt((double)twoSm1 * twoSm1 - 8.0 * (double)p)) * 0.5);
    if (i < 0) i = 0;
    if (i > S - 2) i = S - 2;
#define BASE(ii) ((ii) * (twoSm1 - (ii)) / 2)
    while (i < S - 2 && BASE(i + 1) <= p) ++i;
    while (i > 0 && BASE(i) > p) --i;
    int j = i + 1 + (p - BASE(i));
#undef BASE
    int u0 = nodes[i], u1 = nodes[j];
    float bij = beta[u0] + beta[u1];
    size_t r0 = (size_t)u0 * DD4;
    size_t r1 = (size_t)u1 * DD4;
    float dxt[DD];
#pragma unroll
    for (int q = 0; q < DD4; ++q) {
      float4 a = x04[r0 + q];
      float4 bb = x04[r1 + q];
      dxt[q * 4 + 0] = a.x - bb.x;
      dxt[q * 4 + 1] = a.y - bb.y;
      dxt[q * 4 + 2] = a.z - bb.z;
      dxt[q * 4 + 3] = a.w - bb.w;
    }
    for (int b = 0; b < BINSN; ++b) {
      size_t bo4 = (size_t)b * nd4;
      float sdd = 0.f, sxd = 0.f, sxx = 0.f;
#pragma unroll
      for (int q = 0; q < DD4; ++q) {
        float4 a = v4[bo4 + r0 + q];
        float4 c = v4[bo4 + r1 + q];
        float d0 = a.x - c.x, d1 = a.y - c.y, d2 = a.z - c.z, d3 = a.w - c.w;
        float y0 = dxt[q * 4 + 0], y1 = dxt[q * 4 + 1];
        float y2 = dxt[q * 4 + 2], y3 = dxt[q * 4 + 3];
        sdd += d0 * d0 + d1 * d1 + d2 * d2 + d3 * d3;
        sxd += y0 * d0 + y1 * d1 + y2 * d2 + y3 * d3;
        sxx += y0 * y0 + y1 * y1 + y2 * y2 + y3 * y3;
        dxt[q * 4 + 0] = fmaf(BWF, d0, y0);
        dxt[q * 4 + 1] = fmaf(BWF, d1, y1);
        dxt[q * 4 + 2] = fmaf(BWF, d2, y2);
        dxt[q * 4 + 3] = fmaf(BWF, d3, y3);
      }
      float ndv = sqrtf(sdd);
      float inv = __fdividef(1.0f, ndv + EPSF);
      float r = sxd * inv;
      float t1 = __expf(bij + r * r - sxx);
      float lo = fmaf((float)b * BWF, ndv, r);
      float hi = fmaf((float)(b + 1) * BWF, ndv, r);
      acc += SQRTPI_HALF * inv * t1 * (fast_erff(hi) - fast_erff(lo));
    }
  }
#pragma unroll
  for (int m = 32; m >= 1; m >>= 1) acc += __shfl_xor(acc, m, 64);
  __shared__ float smem[16];
  int wid = threadIdx.x >> 6;
  if ((threadIdx.x & 63) == 0) smem[wid] = acc;
  __syncthreads();
  if (threadIdx.x == 0) {
    float tot = 0.f;
    int nw = blockDim.x >> 6;
    for (int w = 0; w < nw; ++w) tot += smem[w];
    atomicAdd(out, tot);
  }
}

extern "C" void kernel_launch(void* const* d_in, const int* in_sizes, int n_in,
                              void* d_out, int out_size, void* d_ws, size_t ws_size,
                              hipStream_t stream) {
  const float* x0 = (const float*)d_in[0];
  const float* v = (const float*)d_in[1];
  const float* beta = (const float*)d_in[2];
  const float* times = (const float*)d_in[3];
  const int* pairs = (const int*)d_in[4];
  const int* nodes = (const int*)d_in[5];
  int N = in_sizes[2];          // 8192
  int E = in_sizes[3];          // 100000
  int S = in_sizes[5];          // 256
  float* out = (float*)d_out;
  float* P = (float*)d_ws;
  const int ND = N * DD;
  size_t needP = (size_t)BINSN * (size_t)ND * sizeof(float);
  bool useP = (ws_size >= needP);

  hipMemsetAsync(d_out, 0, (size_t)out_size * sizeof(float), stream);

  if (useP) {
    int threads = 256;
    int blocks = (ND + threads - 1) / threads;    // 1024: 16 waves/CU
    pos_kernel<<<blocks, threads, 0, stream>>>(x0, v, P, ND);

    event_kernel_p<<<2048, 256, 0, stream>>>(P, v, beta, times, pairs, N, E, out);

    int ntr = (S + TS - 1) / TS;                  // 16
    int nTiles = ntr * (ntr + 1) / 2;             // 136
    int bchunk = 5;
    int nBinChunks = (BINSN + bchunk - 1) / bchunk;  // 10
    integral_tiled<<<nTiles * nBinChunks, 256, 0, stream>>>(
        (const float4*)P, (const float4*)v, beta, nodes,
        N, S, ntr, nTiles, bchunk, out);
  } else {
    event_kernel_fb<<<2048, 256, 0, stream>>>(x0, v, beta, times, pairs, N, E, out);
    int npair = S * (S - 1) / 2;
    int nPairChunks = (npair + 255) / 256;
    integral_fb<<<nPairChunks, 256, 0, stream>>>(
        (const float4*)x0, (const float4*)v, beta, nodes, N, S, npair,
        nPairChunks, out);
  }
}